// Round 1
// baseline (1400.249 us; speedup 1.0000x reference)
//
#include <hip/hip_runtime.h>
#include <math.h>

// Problem geometry
// conv-as-GEMM: M = 128*36 = 4608 (b,h,w), N = 256 (kcap*32+o), K = 256*81 = 20736
#define M_TOT 4608
#define N_TOT 256
#define K_TOT 20736
#define KSPLIT 4
#define KCHUNK (K_TOT / KSPLIT)   // 5184
#define BM 64
#define BN 64
#define BK 16

// -------------------- conv (implicit im2col GEMM, split-K, atomic accumulate) -----------
__global__ __launch_bounds__(256) void conv_gemm(
    const float* __restrict__ inp,   // [128,256,20,20]
    const float* __restrict__ w,     // [256, 20736]
    float* __restrict__ u)           // [128,1152,8]  (pre-zeroed, atomic accumulate)
{
    __shared__ float As[BK][BM];
    __shared__ float Bs[BK][BN];
    const int tid = threadIdx.x;
    const int m0 = blockIdx.x * BM;
    const int n0 = blockIdx.y * BN;
    const int k_begin = blockIdx.z * KCHUNK;
    const int k_end   = k_begin + KCHUNK;
    const int tx = tid & 15;   // n direction
    const int ty = tid >> 4;   // m direction

    // A-load mapping: thread covers (k = tid>>4, m = (tid&15)*4 .. +3)
    const int a_k = tid >> 4;
    const int a_m = (tid & 15) * 4;
    // hoist per-m input base offsets: addr = base_m + cin*400 + kh*20 + kw
    int base_m[4];
#pragma unroll
    for (int j = 0; j < 4; ++j) {
        int m  = m0 + a_m + j;
        int b  = m / 36;
        int hw = m - b * 36;
        int h  = hw / 6;
        int wo = hw - h * 6;
        base_m[j] = b * 102400 + h * 40 + wo * 2;   // b*256*400 + (2h)*20 + 2wo
    }
    // B-load mapping: thread covers (n = tid>>2, k = (tid&3)*4 .. +3), float4 along k
    const int b_n  = tid >> 2;
    const int b_kq = (tid & 3) * 4;
    const float* bsrc = w + (size_t)(n0 + b_n) * K_TOT + b_kq;

    float acc[4][4] = {};

    for (int k0 = k_begin; k0 < k_end; k0 += BK) {
        // ---- stage A tile ----
        {
            int kk  = k0 + a_k;
            int cin = kk / 81;
            int rem = kk - cin * 81;
            int kh  = rem / 9;
            int kw  = rem - kh * 9;
            int koff = cin * 400 + kh * 20 + kw;
            float t0 = inp[base_m[0] + koff];
            float t1 = inp[base_m[1] + koff];
            float t2 = inp[base_m[2] + koff];
            float t3 = inp[base_m[3] + koff];
            *(float4*)&As[a_k][a_m] = make_float4(t0, t1, t2, t3);
        }
        // ---- stage B tile (coalesced float4 along K) ----
        {
            float4 bv = *(const float4*)(bsrc + k0);
            Bs[b_kq + 0][b_n] = bv.x;
            Bs[b_kq + 1][b_n] = bv.y;
            Bs[b_kq + 2][b_n] = bv.z;
            Bs[b_kq + 3][b_n] = bv.w;
        }
        __syncthreads();
#pragma unroll
        for (int kk = 0; kk < BK; ++kk) {
            float4 av = *(const float4*)&As[kk][ty * 4];
            float4 bv = *(const float4*)&Bs[kk][tx * 4];
            float aa[4] = {av.x, av.y, av.z, av.w};
            float bb[4] = {bv.x, bv.y, bv.z, bv.w};
#pragma unroll
            for (int i = 0; i < 4; ++i)
#pragma unroll
                for (int j = 0; j < 4; ++j)
                    acc[i][j] += aa[i] * bb[j];
        }
        __syncthreads();
    }

    // epilogue: scatter into u[b, r=o*36+hw, kcap] with atomic accumulate (split-K)
#pragma unroll
    for (int i = 0; i < 4; ++i) {
        int m  = m0 + ty * 4 + i;
        int b  = m / 36;
        int hw = m - b * 36;
#pragma unroll
        for (int j = 0; j < 4; ++j) {
            int n    = n0 + tx * 4 + j;
            int kcap = n >> 5;
            int o    = n & 31;
            atomicAdd(&u[((size_t)b * 1152 + o * 36 + hw) * 8 + kcap], acc[i][j]);
        }
    }
}

// -------------------- bias + squash over capsule axis (in-place ok) ---------------------
__global__ __launch_bounds__(256) void combine_squash(
    const float* __restrict__ u_in, const float* __restrict__ bias,
    float* __restrict__ x)
{
    int idx = blockIdx.x * blockDim.x + threadIdx.x;   // (b,r)
    if (idx >= 128 * 1152) return;
    int r = idx % 1152;
    int o = r / 36;
    const float* up = u_in + (size_t)idx * 8;
    float t[8];
    float sn = 0.f;
#pragma unroll
    for (int k = 0; k < 8; ++k) {
        float val = up[k] + bias[k * 32 + o];
        t[k] = val;
        sn += val * val;
    }
    float scale = sqrtf(sn) / (1.f + sn);   // (sn/(1+sn))/sqrt(sn)
    float* xp = x + (size_t)idx * 8;
#pragma unroll
    for (int k = 0; k < 8; ++k) xp[k] = t[k] * scale;
}

// -------------------- reduction helpers -------------------------------------------------
__device__ inline float wave_reduce_sum(float v) {
#pragma unroll
    for (int off = 32; off > 0; off >>= 1) v += __shfl_down(v, off, 64);
    return v;
}
__device__ inline float wave_reduce_max(float v) {
#pragma unroll
    for (int off = 32; off > 0; off >>= 1) v = fmaxf(v, __shfl_down(v, off, 64));
    return v;
}

// s[c,b,o] = sum_r softmax_r(a[c,b,:])[r] * pred[c,b,r,o]; a==null => uniform 1/1152
__global__ __launch_bounds__(256) void compute_s(
    const float* __restrict__ x,   // [128,1152,8]
    const float* __restrict__ rw,  // [10,1152,8,16]
    const float* __restrict__ a,   // [10,128,1152] or null
    float* __restrict__ s)         // [10,128,16]
{
    const int c = blockIdx.x, b = blockIdx.y, tid = threadIdx.x;
    const int wave = tid >> 6, lane = tid & 63;
    __shared__ float lred[4];
    __shared__ float ored[16][4];

    const float* ab = a ? (a + ((size_t)c * 128 + b) * 1152) : nullptr;
    float wmax = 0.f, winv = 0.f;
    if (a) {
        float mx = -1e30f;
        for (int r = tid; r < 1152; r += 256) mx = fmaxf(mx, ab[r]);
        mx = wave_reduce_max(mx);
        if (lane == 0) lred[wave] = mx;
        __syncthreads();
        wmax = fmaxf(fmaxf(lred[0], lred[1]), fmaxf(lred[2], lred[3]));
        __syncthreads();
        float e = 0.f;
        for (int r = tid; r < 1152; r += 256) e += __expf(ab[r] - wmax);
        e = wave_reduce_sum(e);
        if (lane == 0) lred[wave] = e;
        __syncthreads();
        winv = 1.f / (lred[0] + lred[1] + lred[2] + lred[3]);
    }

    float acc[16];
#pragma unroll
    for (int o = 0; o < 16; ++o) acc[o] = 0.f;

    for (int r = tid; r < 1152; r += 256) {
        float weight = a ? __expf(ab[r] - wmax) * winv : (1.f / 1152.f);
        const float* xr = x + ((size_t)b * 1152 + r) * 8;
        const float* wr = rw + ((size_t)c * 1152 + r) * 128;
        float wx[8];
#pragma unroll
        for (int k = 0; k < 8; ++k) wx[k] = weight * xr[k];
#pragma unroll
        for (int k = 0; k < 8; ++k) {
            const float4* wp = (const float4*)(wr + k * 16);
            float4 w0 = wp[0], w1 = wp[1], w2 = wp[2], w3 = wp[3];
            float xk = wx[k];
            acc[0]  += xk * w0.x;  acc[1]  += xk * w0.y;
            acc[2]  += xk * w0.z;  acc[3]  += xk * w0.w;
            acc[4]  += xk * w1.x;  acc[5]  += xk * w1.y;
            acc[6]  += xk * w1.z;  acc[7]  += xk * w1.w;
            acc[8]  += xk * w2.x;  acc[9]  += xk * w2.y;
            acc[10] += xk * w2.z;  acc[11] += xk * w2.w;
            acc[12] += xk * w3.x;  acc[13] += xk * w3.y;
            acc[14] += xk * w3.z;  acc[15] += xk * w3.w;
        }
    }
#pragma unroll
    for (int o = 0; o < 16; ++o) {
        float vsum = wave_reduce_sum(acc[o]);
        if (lane == 0) ored[o][wave] = vsum;
    }
    __syncthreads();
    if (tid < 16) {
        float t = ored[tid][0] + ored[tid][1] + ored[tid][2] + ored[tid][3];
        s[((size_t)c * 128 + b) * 16 + tid] = t;
    }
}

// a_out[c,b,r] = (a_in ? a_in : 0) + sum_o pred[c,b,r,o] * v[c,b,o]
__global__ __launch_bounds__(256) void update_a(
    const float* __restrict__ x, const float* __restrict__ rw,
    const float* __restrict__ v, const float* __restrict__ a_in,
    float* __restrict__ a_out)
{
    const int c = blockIdx.x, b = blockIdx.y, tid = threadIdx.x;
    __shared__ float vs[16];
    if (tid < 16) vs[tid] = v[((size_t)c * 128 + b) * 16 + tid];
    __syncthreads();
    for (int r = tid; r < 1152; r += 256) {
        const float* xr = x + ((size_t)b * 1152 + r) * 8;
        const float* wr = rw + ((size_t)c * 1152 + r) * 128;
        float dot = 0.f;
#pragma unroll
        for (int k = 0; k < 8; ++k) {
            const float4* wp = (const float4*)(wr + k * 16);
            float4 w0 = wp[0], w1 = wp[1], w2 = wp[2], w3 = wp[3];
            float t = w0.x * vs[0] + w0.y * vs[1] + w0.z * vs[2] + w0.w * vs[3]
                    + w1.x * vs[4] + w1.y * vs[5] + w1.z * vs[6] + w1.w * vs[7]
                    + w2.x * vs[8] + w2.y * vs[9] + w2.z * vs[10] + w2.w * vs[11]
                    + w3.x * vs[12] + w3.y * vs[13] + w3.z * vs[14] + w3.w * vs[15];
            dot += xr[k] * t;
        }
        size_t ai = ((size_t)c * 128 + b) * 1152 + r;
        a_out[ai] = (a_in ? a_in[ai] : 0.f) + dot;
    }
}

// v = squash(s, axis=batch)  [faithful to reference's axis=1 over B]
// final_out != null -> write out[b,c,o] (the transposed final output)
__global__ __launch_bounds__(128) void squash_v(
    const float* __restrict__ s, float* __restrict__ v_out,
    float* __restrict__ final_out)
{
    const int c = blockIdx.x, b = threadIdx.x;   // 10 blocks, 128 threads
    float sv[16];
    const float* sp = s + ((size_t)c * 128 + b) * 16;
#pragma unroll
    for (int o = 0; o < 16; ++o) sv[o] = sp[o];
    __shared__ float m[16][129];
#pragma unroll
    for (int o = 0; o < 16; ++o) m[o][b] = sv[o] * sv[o];
    __syncthreads();
    __shared__ float sn[16];
    if (b < 16) {
        float t = 0.f;
        for (int i = 0; i < 128; ++i) t += m[b][i];
        sn[b] = t;
    }
    __syncthreads();
#pragma unroll
    for (int o = 0; o < 16; ++o) {
        float scale = sqrtf(sn[o]) / (1.f + sn[o]);
        float val = sv[o] * scale;
        if (final_out) final_out[((size_t)b * 10 + c) * 16 + o] = val;
        else           v_out[((size_t)c * 128 + b) * 16 + o] = val;
    }
}

// -------------------- launch ------------------------------------------------------------
extern "C" void kernel_launch(void* const* d_in, const int* in_sizes, int n_in,
                              void* d_out, int out_size, void* d_ws, size_t ws_size,
                              hipStream_t stream)
{
    (void)in_sizes; (void)n_in; (void)out_size; (void)ws_size;
    const float* inp = (const float*)d_in[0];   // [128,256,20,20]
    const float* cw  = (const float*)d_in[1];   // [8,32,256,9,9] == [256,20736]
    const float* cb  = (const float*)d_in[2];   // [8,32]
    const float* rw  = (const float*)d_in[3];   // [10,1152,8,16]
    float* out = (float*)d_out;                 // [128,10,16]

    // workspace layout (floats): u 1,179,648 | a 1,474,560 | s 20,480 | v 20,480  (~10.8 MB)
    float* u = (float*)d_ws;
    float* a = u + 1179648;
    float* s = a + 1474560;
    float* v = s + 20480;

    hipMemsetAsync(u, 0, (size_t)1179648 * sizeof(float), stream);
    conv_gemm<<<dim3(M_TOT / BM, N_TOT / BN, KSPLIT), 256, 0, stream>>>(inp, cw, u);
    combine_squash<<<(128 * 1152 + 255) / 256, 256, 0, stream>>>(u, cb, u);

    // routing, NUM_ITERS = 3
    compute_s<<<dim3(10, 128), 256, 0, stream>>>(u, rw, nullptr, s);   // i=0, uniform c
    squash_v<<<10, 128, 0, stream>>>(s, v, nullptr);                   // v0
    update_a<<<dim3(10, 128), 256, 0, stream>>>(u, rw, v, nullptr, a); // a1
    compute_s<<<dim3(10, 128), 256, 0, stream>>>(u, rw, a, s);         // i=1
    squash_v<<<10, 128, 0, stream>>>(s, v, nullptr);                   // v1
    update_a<<<dim3(10, 128), 256, 0, stream>>>(u, rw, v, a, a);       // a2
    compute_s<<<dim3(10, 128), 256, 0, stream>>>(u, rw, a, s);         // i=2
    squash_v<<<10, 128, 0, stream>>>(s, nullptr, out);                 // v2 -> out
}

// Round 2
// 705.383 us; speedup vs baseline: 1.9851x; 1.9851x over previous
//
#include <hip/hip_runtime.h>
#include <math.h>

typedef _Float16 f16;
typedef _Float16 f16x8 __attribute__((ext_vector_type(8)));
typedef float f32x4 __attribute__((ext_vector_type(4)));

#define AS1 __attribute__((address_space(1)))
#define AS3 __attribute__((address_space(3)))

__device__ __forceinline__ void gld_lds16(const f16* g, f16* l) {
#if defined(__has_builtin) && __has_builtin(__builtin_amdgcn_global_load_lds)
    __builtin_amdgcn_global_load_lds((const AS1 void*)g, (AS3 void*)l, 16, 0, 0);
#else
    *(uint4*)l = *(const uint4*)g;
#endif
}

// ---------------- pre-pass 1: input [128,256,20,20] f32 -> [128,20,20,256] f16 ----------
__global__ __launch_bounds__(256) void transpose_input(
    const float* __restrict__ inp, f16* __restrict__ out)
{
    const int b = blockIdx.x, c0 = blockIdx.y * 32, p0 = blockIdx.z * 32;
    const int tx = threadIdx.x, ty = threadIdx.y;   // 32 x 8
    __shared__ float t[32][33];
#pragma unroll
    for (int j = 0; j < 4; ++j) {
        int c = ty + j * 8, p = p0 + tx;
        if (p < 400) t[c][tx] = inp[((size_t)b * 256 + c0 + c) * 400 + p];
    }
    __syncthreads();
#pragma unroll
    for (int j = 0; j < 4; ++j) {
        int p = p0 + ty + j * 8;
        if (p < 400) out[((size_t)b * 400 + p) * 256 + c0 + tx] = (f16)t[tx][ty + j * 8];
    }
}

// ---------------- pre-pass 2: conv_w [n=256][cin=256][p=81] f32 -> w_t[n][p*256+cin] f16 -
__global__ __launch_bounds__(256) void permute_w(
    const float* __restrict__ cw, f16* __restrict__ w_t)
{
    const int n = blockIdx.x, t = threadIdx.x;
    __shared__ f16 buf[81 * 258];
    const float* src = cw + (size_t)n * 20736;
    for (int i = t; i < 20736; i += 256) {
        int cin = i / 81, p = i - cin * 81;
        buf[p * 258 + cin] = (f16)src[i];
    }
    __syncthreads();
    f16* dst = w_t + (size_t)n * 20736;
    for (int j = t; j < 20736; j += 256) {
        int p = j >> 8, cin = j & 255;
        dst[j] = buf[p * 258 + cin];
    }
}

// ---------------- conv as implicit-im2col MFMA GEMM -------------------------------------
// M=4608 (b,ho,wo), N=256 (kcap*32+o), K'=20736 ordered (kh,kw,cin). Tiles 128x64, BK=64,
// split-K=4, atomic fp32 accumulate into u[128,1152,8].
__global__ __launch_bounds__(256) void conv_mfma(
    const f16* __restrict__ in_t,   // [128,20,20,256]
    const f16* __restrict__ w_t,    // [256,20736]
    float* __restrict__ u)
{
    __shared__ f16 As[128 * 64];
    __shared__ f16 Bs[64 * 64];
    const int tid = threadIdx.x;
    const int lane = tid & 63, wave = tid >> 6;
    const int wm = wave >> 1, wn = wave & 1;
    const int m0 = blockIdx.x * 128, n0 = blockIdx.y * 64;
    const int kz = blockIdx.z;

    // staging maps: lane covers 16B chunk (m = i*32 + tid>>3, phys chunk = tid&7)
    const int lc = (tid & 7) ^ ((tid >> 3) & 7);   // XOR-swizzle source chunk
    int pixA[4];
#pragma unroll
    for (int i = 0; i < 4; ++i) {
        int m = m0 + i * 32 + (tid >> 3);
        int b = m / 36, hw = m - b * 36;
        int ho = hw / 6, wo = hw - ho * 6;
        pixA[i] = ((b * 20 + 2 * ho) * 20 + 2 * wo) * 256 + lc * 8;
    }
    int wB[2];
#pragma unroll
    for (int i = 0; i < 2; ++i) {
        int n = n0 + i * 32 + (tid >> 3);
        wB[i] = n * 20736 + lc * 8;
    }
    f16* ldsA = As + tid * 8;
    f16* ldsB = Bs + tid * 8;

    f32x4 acc[4][2] = {};
    const int row = lane & 15, quad = lane >> 4;

    for (int it = 0; it < 81; ++it) {
        int kc = kz * 81 + it;
        int p = kc >> 2, cq = kc & 3;
        int kh = p / 9, kw = p - kh * 9;
        int koffA = (kh * 20 + kw) * 256 + cq * 64;
        int koffB = kc * 64;
        __syncthreads();
#pragma unroll
        for (int i = 0; i < 4; ++i)
            gld_lds16(in_t + pixA[i] + koffA, ldsA + i * 2048);
#pragma unroll
        for (int i = 0; i < 2; ++i)
            gld_lds16(w_t + wB[i] + koffB, ldsB + i * 2048);
        __syncthreads();

#pragma unroll
        for (int kk = 0; kk < 2; ++kk) {
            f16x8 af[4], bf[2];
#pragma unroll
            for (int mt = 0; mt < 4; ++mt) {
                int m = wm * 64 + mt * 16 + row;
                int ph = (kk * 4 + quad) ^ (m & 7);
                af[mt] = *(const f16x8*)(As + m * 64 + ph * 8);
            }
#pragma unroll
            for (int nt = 0; nt < 2; ++nt) {
                int n = wn * 32 + nt * 16 + row;
                int ph = (kk * 4 + quad) ^ (n & 7);
                bf[nt] = *(const f16x8*)(Bs + n * 64 + ph * 8);
            }
#pragma unroll
            for (int mt = 0; mt < 4; ++mt)
#pragma unroll
                for (int nt = 0; nt < 2; ++nt)
                    acc[mt][nt] = __builtin_amdgcn_mfma_f32_16x16x32_f16(
                        af[mt], bf[nt], acc[mt][nt], 0, 0, 0);
        }
    }

    const int col = lane & 15, qr = (lane >> 4) * 4;
#pragma unroll
    for (int mt = 0; mt < 4; ++mt)
#pragma unroll
        for (int rg = 0; rg < 4; ++rg) {
            int m = m0 + wm * 64 + mt * 16 + qr + rg;
            int b = m / 36, hw = m - b * 36;
#pragma unroll
            for (int nt = 0; nt < 2; ++nt) {
                int n = n0 + wn * 32 + nt * 16 + col;
                int o = n & 31, kcap = n >> 5;
                atomicAdd(u + ((size_t)(b * 1152 + o * 36 + hw) << 3) + kcap,
                          acc[mt][nt][rg]);
            }
        }
}

// ---------------- bias + squash over capsule axis (in-place) ----------------------------
__global__ __launch_bounds__(256) void combine_squash(
    const float* __restrict__ u_in, const float* __restrict__ bias,
    float* __restrict__ x)
{
    int idx = blockIdx.x * blockDim.x + threadIdx.x;   // (b,r)
    if (idx >= 128 * 1152) return;
    int r = idx % 1152;
    int o = r / 36;
    const float* up = u_in + (size_t)idx * 8;
    float t[8];
    float sn = 0.f;
#pragma unroll
    for (int k = 0; k < 8; ++k) {
        float val = up[k] + bias[k * 32 + o];
        t[k] = val;
        sn += val * val;
    }
    float scale = sqrtf(sn) / (1.f + sn);
    float* xp = x + (size_t)idx * 8;
#pragma unroll
    for (int k = 0; k < 8; ++k) xp[k] = t[k] * scale;
}

// ---------------- one routing iteration (fused logit-update + weighted sum) -------------
// For each (c,b): a_new[r] = a_old[r] + pred[r]·v  (skipped when v_in==null, e=1)
//                 e[r] = exp(a_new[r]);  s_acc[c,b,o] += sum_r e[r]*pred[r,o];  z += sum e
// softmax normalization deferred to squash_v (s = s_acc/z).
__global__ __launch_bounds__(256) void route_iter(
    const float* __restrict__ x,    // [128,1152,8]
    const float* __restrict__ rw,   // [10,1152,8,16]
    const float* __restrict__ v_in, // [10,128,16] or null
    const float* __restrict__ a_in, // [10,128,1152] or null
    float* __restrict__ a_out,
    float* __restrict__ s_acc,      // [10,128,16] zeroed
    float* __restrict__ z_acc)      // [10,128]   zeroed
{
    const int c = blockIdx.x, r0 = blockIdx.y * 128, b0 = blockIdx.z * 32;
    const int tid = threadIdx.x;
    const int o = tid & 15, rsub = tid >> 4;       // rsub 0..15, 8 routes each
    const int lane = tid & 63, wave = tid >> 6;

    __shared__ float xs[128][8];
    __shared__ float vs[32][16];
    __shared__ float wpart[4][16];
    __shared__ float zpart[4];

    // route weights held in registers: Wreg[rl][k] = rw[c][r0+rsub*8+rl][k][o]
    float Wreg[8][8];
    {
        const float* base = rw + ((size_t)c * 1152 + r0 + rsub * 8) * 128 + o;
#pragma unroll
        for (int rl = 0; rl < 8; ++rl)
#pragma unroll
            for (int k = 0; k < 8; ++k)
                Wreg[rl][k] = base[rl * 128 + k * 16];
    }
    if (v_in) {
        int bb = tid >> 4;
        vs[bb][o]      = v_in[((size_t)c * 128 + b0 + bb) * 16 + o];
        vs[bb + 16][o] = v_in[((size_t)c * 128 + b0 + bb + 16) * 16 + o];
    }

    for (int bb = 0; bb < 32; ++bb) {
        const int b = b0 + bb;
        __syncthreads();
        {   // stage x rows for this b
            int rr = tid >> 1, k4 = (tid & 1) * 4;
            *(float4*)&xs[rr][k4] =
                *(const float4*)(x + ((size_t)b * 1152 + r0 + rr) * 8 + k4);
        }
        __syncthreads();

        float sacc = 0.f, zacc = 0.f;
#pragma unroll
        for (int rl = 0; rl < 8; ++rl) {
            int rr = rsub * 8 + rl;
            float4 x0 = *(const float4*)&xs[rr][0];
            float4 x1 = *(const float4*)&xs[rr][4];
            float wv = x0.x * Wreg[rl][0] + x0.y * Wreg[rl][1]
                     + x0.z * Wreg[rl][2] + x0.w * Wreg[rl][3]
                     + x1.x * Wreg[rl][4] + x1.y * Wreg[rl][5]
                     + x1.z * Wreg[rl][6] + x1.w * Wreg[rl][7];   // pred[r][o]
            float e;
            if (v_in) {
                float contrib = wv * vs[bb][o];
                contrib += __shfl_xor(contrib, 1);
                contrib += __shfl_xor(contrib, 2);
                contrib += __shfl_xor(contrib, 4);
                contrib += __shfl_xor(contrib, 8);    // dot over all 16 o
                size_t aidx = ((size_t)c * 128 + b) * 1152 + r0 + rr;
                float an = (a_in ? a_in[aidx] : 0.f) + contrib;
                if (o == 0) a_out[aidx] = an;
                e = __expf(an);
            } else {
                e = 1.f;
            }
            sacc += e * wv;
            zacc += e;
        }
        sacc += __shfl_xor(sacc, 16);
        sacc += __shfl_xor(sacc, 32);
        zacc += __shfl_xor(zacc, 16);
        zacc += __shfl_xor(zacc, 32);
        if (lane < 16) wpart[wave][lane] = sacc;
        if (lane == 0) zpart[wave] = zacc;
        __syncthreads();
        if (tid < 16) {
            float t = wpart[0][tid] + wpart[1][tid] + wpart[2][tid] + wpart[3][tid];
            atomicAdd(s_acc + ((size_t)c * 128 + b) * 16 + tid, t);
        } else if (tid == 16) {
            atomicAdd(z_acc + c * 128 + b, zpart[0] + zpart[1] + zpart[2] + zpart[3]);
        }
    }
}

// ---------------- v = squash(s_acc/z, axis=batch); optionally final output --------------
__global__ __launch_bounds__(128) void squash_v(
    const float* __restrict__ s, const float* __restrict__ z,
    float* __restrict__ v_out, float* __restrict__ final_out)
{
    const int c = blockIdx.x, b = threadIdx.x;   // 10 blocks, 128 threads
    float sv[16];
    const float* sp = s + ((size_t)c * 128 + b) * 16;
    float zin = 1.f / z[c * 128 + b];
#pragma unroll
    for (int o = 0; o < 16; ++o) sv[o] = sp[o] * zin;
    __shared__ float m[16][129];
#pragma unroll
    for (int o = 0; o < 16; ++o) m[o][b] = sv[o] * sv[o];
    __syncthreads();
    __shared__ float sn[16];
    if (b < 16) {
        float t = 0.f;
        for (int i = 0; i < 128; ++i) t += m[b][i];
        sn[b] = t;
    }
    __syncthreads();
#pragma unroll
    for (int o = 0; o < 16; ++o) {
        float scale = sqrtf(sn[o]) / (1.f + sn[o]);
        float val = sv[o] * scale;
        if (final_out) final_out[((size_t)b * 10 + c) * 16 + o] = val;
        else           v_out[((size_t)c * 128 + b) * 16 + o] = val;
    }
}

// ---------------- launch ----------------------------------------------------------------
extern "C" void kernel_launch(void* const* d_in, const int* in_sizes, int n_in,
                              void* d_out, int out_size, void* d_ws, size_t ws_size,
                              hipStream_t stream)
{
    (void)in_sizes; (void)n_in; (void)out_size; (void)ws_size;
    const float* inp = (const float*)d_in[0];
    const float* cw  = (const float*)d_in[1];
    const float* cb  = (const float*)d_in[2];
    const float* rw  = (const float*)d_in[3];
    float* out = (float*)d_out;

    char* ws = (char*)d_ws;
    float* u   = (float*)(ws);               // 4,718,592 B  [128,1152,8]
    float* a   = (float*)(ws + 4718592);     // 5,898,240 B  [10,128,1152]
    float* s   = (float*)(ws + 10616832);    //    81,920 B  [10,128,16]
    float* z   = (float*)(ws + 10698752);    //     5,120 B  [10,128]
    float* v   = (float*)(ws + 10703872);    //    81,920 B  [10,128,16]
    f16*   in_t = (f16*)(ws + 10785792);     // 26,214,400 B [128,20,20,256]
    f16*   w_t  = (f16*)(ws + 37000192);     // 10,616,832 B [256,20736]  (total ~47.6 MB)

    hipMemsetAsync(u, 0, 4718592, stream);
    transpose_input<<<dim3(128, 8, 13), dim3(32, 8), 0, stream>>>(inp, in_t);
    permute_w<<<256, 256, 0, stream>>>(cw, w_t);
    conv_mfma<<<dim3(36, 4, 4), 256, 0, stream>>>(in_t, w_t, u);
    combine_squash<<<576, 256, 0, stream>>>(u, cb, u);

    // routing: 3 iterations, unnormalized-softmax accumulation
    hipMemsetAsync(s, 0, 87040, stream);    // s + z (adjacent)
    route_iter<<<dim3(10, 9, 4), 256, 0, stream>>>(u, rw, nullptr, nullptr, a, s, z);
    squash_v<<<10, 128, 0, stream>>>(s, z, v, nullptr);
    hipMemsetAsync(s, 0, 87040, stream);
    route_iter<<<dim3(10, 9, 4), 256, 0, stream>>>(u, rw, v, nullptr, a, s, z);
    squash_v<<<10, 128, 0, stream>>>(s, z, v, nullptr);
    hipMemsetAsync(s, 0, 87040, stream);
    route_iter<<<dim3(10, 9, 4), 256, 0, stream>>>(u, rw, v, a, a, s, z);
    squash_v<<<10, 128, 0, stream>>>(s, z, nullptr, out);
}

// Round 3
// 300.056 us; speedup vs baseline: 4.6666x; 2.3508x over previous
//
#include <hip/hip_runtime.h>
#include <math.h>

typedef _Float16 f16;
typedef _Float16 f16x8 __attribute__((ext_vector_type(8)));
typedef float f32x4 __attribute__((ext_vector_type(4)));

#define AS1 __attribute__((address_space(1)))
#define AS3 __attribute__((address_space(3)))

__device__ __forceinline__ void gld_lds16(const f16* g, f16* l) {
#if defined(__has_builtin) && __has_builtin(__builtin_amdgcn_global_load_lds)
    __builtin_amdgcn_global_load_lds((const AS1 void*)g, (AS3 void*)l, 16, 0, 0);
#else
    *(uint4*)l = *(const uint4*)g;
#endif
}

// ---------------- pre-pass 1: input [128,256,20,20] f32 -> [128,20,20,256] f16 ----------
__global__ __launch_bounds__(256) void transpose_input(
    const float* __restrict__ inp, f16* __restrict__ out)
{
    const int b = blockIdx.x, c0 = blockIdx.y * 32, p0 = blockIdx.z * 32;
    const int tx = threadIdx.x, ty = threadIdx.y;   // 32 x 8
    __shared__ float t[32][33];
#pragma unroll
    for (int j = 0; j < 4; ++j) {
        int c = ty + j * 8, p = p0 + tx;
        if (p < 400) t[c][tx] = inp[((size_t)b * 256 + c0 + c) * 400 + p];
    }
    __syncthreads();
#pragma unroll
    for (int j = 0; j < 4; ++j) {
        int p = p0 + ty + j * 8;
        if (p < 400) out[((size_t)b * 400 + p) * 256 + c0 + tx] = (f16)t[tx][ty + j * 8];
    }
}

// ---------------- pre-pass 2: conv_w [n=256][cin=256][p=81] f32 -> w_t[n][p*256+cin] f16 -
__global__ __launch_bounds__(256) void permute_w(
    const float* __restrict__ cw, f16* __restrict__ w_t)
{
    const int n = blockIdx.x, t = threadIdx.x;
    __shared__ f16 buf[81 * 258];
    const float* src = cw + (size_t)n * 20736;
    for (int i = t; i < 20736; i += 256) {
        int cin = i / 81, p = i - cin * 81;
        buf[p * 258 + cin] = (f16)src[i];
    }
    __syncthreads();
    f16* dst = w_t + (size_t)n * 20736;
    for (int j = t; j < 20736; j += 256) {
        int p = j >> 8, cin = j & 255;
        dst[j] = buf[p * 258 + cin];
    }
}

// ---------------- conv as implicit-im2col MFMA GEMM, double-buffered, split-K=6 ---------
// M=4608 (b,ho,wo), N=256, K = 324 chunks of 64 (ordered kh,kw,cin). 64x64 tiles.
// Writes partial[kz][m][n] (non-atomic, coalesced).
#define SPLITK 6
#define NIT 54   // 324 / 6
__global__ __launch_bounds__(256) void conv_mfma(
    const f16* __restrict__ in_t,   // [128,20,20,256]
    const f16* __restrict__ w_t,    // [256,20736]
    float* __restrict__ part)       // [6,4608,256]
{
    __shared__ f16 As[2][64 * 64];
    __shared__ f16 Bs[2][64 * 64];
    const int tid = threadIdx.x;
    const int lane = tid & 63, wave = tid >> 6;
    const int wm = wave >> 1, wn = wave & 1;
    const int m0 = blockIdx.x * 64, n0 = blockIdx.y * 64;
    const int kz = blockIdx.z;

    const int lc = (tid & 7) ^ ((tid >> 3) & 7);   // XOR-swizzled source chunk
    int pixA[2], wB[2];
#pragma unroll
    for (int i = 0; i < 2; ++i) {
        int m = m0 + i * 32 + (tid >> 3);
        int b = m / 36, hw = m - b * 36;
        int ho = hw / 6, wo = hw - ho * 6;
        pixA[i] = ((b * 20 + 2 * ho) * 20 + 2 * wo) * 256 + lc * 8;
        int n = n0 + i * 32 + (tid >> 3);
        wB[i] = n * 20736 + lc * 8;
    }

    f32x4 acc[2][2] = {};
    const int row = lane & 15, quad = lane >> 4;
    const int kc_base = kz * NIT;

    // ---- prologue: stage chunk 0 into buf 0 ----
    {
        int kc = kc_base;
        int p = kc >> 2, cq = kc & 3;
        int kh = p / 9, kw = p - kh * 9;
        int koffA = (kh * 20 + kw) * 256 + cq * 64;
        int koffB = kc * 64;
#pragma unroll
        for (int i = 0; i < 2; ++i) {
            gld_lds16(in_t + pixA[i] + koffA, &As[0][i * 2048 + tid * 8]);
            gld_lds16(w_t + wB[i] + koffB, &Bs[0][i * 2048 + tid * 8]);
        }
    }

    for (int it = 0; it < NIT; ++it) {
        const int cur = it & 1;
        __syncthreads();   // buf[cur] loads complete; buf[cur^1] readers done
        if (it + 1 < NIT) {
            int kc = kc_base + it + 1;
            int p = kc >> 2, cq = kc & 3;
            int kh = p / 9, kw = p - kh * 9;
            int koffA = (kh * 20 + kw) * 256 + cq * 64;
            int koffB = kc * 64;
#pragma unroll
            for (int i = 0; i < 2; ++i) {
                gld_lds16(in_t + pixA[i] + koffA, &As[cur ^ 1][i * 2048 + tid * 8]);
                gld_lds16(w_t + wB[i] + koffB, &Bs[cur ^ 1][i * 2048 + tid * 8]);
            }
        }
#pragma unroll
        for (int kk = 0; kk < 2; ++kk) {
            f16x8 af[2], bf[2];
#pragma unroll
            for (int mt = 0; mt < 2; ++mt) {
                int m = wm * 32 + mt * 16 + row;
                int ph = (kk * 4 + quad) ^ (m & 7);
                af[mt] = *(const f16x8*)(&As[cur][m * 64 + ph * 8]);
            }
#pragma unroll
            for (int nt = 0; nt < 2; ++nt) {
                int n = wn * 32 + nt * 16 + row;
                int ph = (kk * 4 + quad) ^ (n & 7);
                bf[nt] = *(const f16x8*)(&Bs[cur][n * 64 + ph * 8]);
            }
#pragma unroll
            for (int mt = 0; mt < 2; ++mt)
#pragma unroll
                for (int nt = 0; nt < 2; ++nt)
                    acc[mt][nt] = __builtin_amdgcn_mfma_f32_16x16x32_f16(
                        af[mt], bf[nt], acc[mt][nt], 0, 0, 0);
        }
    }

    // epilogue: coalesced stores to partial buffer
    const int col = lane & 15, qr = (lane >> 4) * 4;
    float* pbase = part + (size_t)kz * 4608 * 256;
#pragma unroll
    for (int mt = 0; mt < 2; ++mt)
#pragma unroll
        for (int rg = 0; rg < 4; ++rg) {
            int m = m0 + wm * 32 + mt * 16 + qr + rg;
#pragma unroll
            for (int nt = 0; nt < 2; ++nt) {
                int n = n0 + wn * 32 + nt * 16 + col;
                pbase[(size_t)m * 256 + n] = acc[mt][nt][rg];
            }
        }
}

// ---------------- split-K reduce + bias + capsule squash -> x[128,1152,8] ---------------
__global__ __launch_bounds__(256) void combine_squash(
    const float* __restrict__ part, const float* __restrict__ bias,
    float* __restrict__ x)
{
    int idx = blockIdx.x * 256 + threadIdx.x;   // over 4608*32
    int m = idx >> 5, o = idx & 31;
    int b = m / 36, hw = m - b * 36;
    float val[8];
#pragma unroll
    for (int k = 0; k < 8; ++k) val[k] = bias[k * 32 + o];
#pragma unroll
    for (int s = 0; s < SPLITK; ++s) {
        const float* p = part + ((size_t)s * 4608 + m) * 256 + o;
#pragma unroll
        for (int k = 0; k < 8; ++k) val[k] += p[k * 32];
    }
    float sn = 0.f;
#pragma unroll
    for (int k = 0; k < 8; ++k) sn += val[k] * val[k];
    float scale = sqrtf(sn) / (1.f + sn);
    int r = o * 36 + hw;
    float* xp = x + ((size_t)b * 1152 + r) * 8;
#pragma unroll
    for (int k = 0; k < 8; ++k) xp[k] = val[k] * scale;
}

// ---------------- pred[c,b,r,o] = sum_k x[b,r,k] * rw[c,r,k,o]  (f32) -------------------
__global__ __launch_bounds__(256) void pred_kernel(
    const float* __restrict__ x, const float* __restrict__ rw,
    float* __restrict__ pred)
{
    const int c = blockIdx.x, r0 = blockIdx.y * 32, b0 = blockIdx.z * 32;
    const int tid = threadIdx.x;
    const int o = tid & 15, rp = tid >> 4;
    const int r = r0 + rp * 2;

    float W0[8], W1[8];
    const float* wb = rw + ((size_t)(c * 1152 + r) * 8) * 16 + o;
#pragma unroll
    for (int k = 0; k < 8; ++k) { W0[k] = wb[k * 16]; W1[k] = wb[128 + k * 16]; }

    for (int b = b0; b < b0 + 32; ++b) {
        const float4* xp = (const float4*)(x + ((size_t)b * 1152 + r) * 8);
        float4 xa = xp[0], xb = xp[1], xc = xp[2], xd = xp[3];
        float p0 = xa.x * W0[0] + xa.y * W0[1] + xa.z * W0[2] + xa.w * W0[3]
                 + xb.x * W0[4] + xb.y * W0[5] + xb.z * W0[6] + xb.w * W0[7];
        float p1 = xc.x * W1[0] + xc.y * W1[1] + xc.z * W1[2] + xc.w * W1[3]
                 + xd.x * W1[4] + xd.y * W1[5] + xd.z * W1[6] + xd.w * W1[7];
        float* pb = pred + ((size_t)(c * 128 + b) * 1152 + r) * 16 + o;
        pb[0]  = p0;
        pb[16] = p1;
    }
}

// ---------------- one routing iteration: block per (c,b), thread per route --------------
// v_in==null: e=1 (uniform).  else an = (a_in?a_in:0) + pred.v ; e=exp(an); opt a_out.
// Writes s_out[c,b,16] (unnormalized) and z_out[c,b] directly.
__global__ __launch_bounds__(256) void route2(
    const float* __restrict__ pred, const float* __restrict__ v_in,
    const float* __restrict__ a_in, float* __restrict__ a_out,
    float* __restrict__ s_out, float* __restrict__ z_out)
{
    const int c = blockIdx.x, b = blockIdx.y, tid = threadIdx.x;
    const size_t base = (size_t)(c * 128 + b) * 1152;

    __shared__ float vs[16];
    __shared__ float red[256][16];
    __shared__ float red2[16][16];
    __shared__ float zred[256];
    __shared__ float zpart[16];

    if (v_in && tid < 16) vs[tid] = v_in[(size_t)(c * 128 + b) * 16 + tid];
    __syncthreads();

    float sacc[16];
#pragma unroll
    for (int o = 0; o < 16; ++o) sacc[o] = 0.f;
    float zacc = 0.f;

    for (int r = tid; r < 1152; r += 256) {
        const float4* pp = (const float4*)(pred + (base + r) * 16);
        float4 q0 = pp[0], q1 = pp[1], q2 = pp[2], q3 = pp[3];
        float e;
        if (v_in) {
            float contrib = q0.x * vs[0] + q0.y * vs[1] + q0.z * vs[2] + q0.w * vs[3]
                          + q1.x * vs[4] + q1.y * vs[5] + q1.z * vs[6] + q1.w * vs[7]
                          + q2.x * vs[8] + q2.y * vs[9] + q2.z * vs[10] + q2.w * vs[11]
                          + q3.x * vs[12] + q3.y * vs[13] + q3.z * vs[14] + q3.w * vs[15];
            float an = contrib + (a_in ? a_in[base + r] : 0.f);
            if (a_out) a_out[base + r] = an;
            e = __expf(an);
        } else {
            e = 1.f;
        }
        sacc[0] += e * q0.x;  sacc[1] += e * q0.y;  sacc[2] += e * q0.z;  sacc[3] += e * q0.w;
        sacc[4] += e * q1.x;  sacc[5] += e * q1.y;  sacc[6] += e * q1.z;  sacc[7] += e * q1.w;
        sacc[8] += e * q2.x;  sacc[9] += e * q2.y;  sacc[10] += e * q2.z; sacc[11] += e * q2.w;
        sacc[12] += e * q3.x; sacc[13] += e * q3.y; sacc[14] += e * q3.z; sacc[15] += e * q3.w;
        zacc += e;
    }

#pragma unroll
    for (int o = 0; o < 16; ++o) red[tid][o] = sacc[o];
    zred[tid] = zacc;
    __syncthreads();
    {
        const int o = tid & 15, seg = tid >> 4;
        float t = 0.f;
#pragma unroll
        for (int j = 0; j < 16; ++j) t += red[seg * 16 + j][o];
        red2[seg][o] = t;
        if (tid < 16) {
            float tz = 0.f;
#pragma unroll
            for (int j = 0; j < 16; ++j) tz += zred[tid * 16 + j];
            zpart[tid] = tz;
        }
    }
    __syncthreads();
    if (tid < 16) {
        float t = 0.f;
#pragma unroll
        for (int seg = 0; seg < 16; ++seg) t += red2[seg][tid];
        s_out[(size_t)(c * 128 + b) * 16 + tid] = t;
    } else if (tid == 16) {
        float tz = 0.f;
#pragma unroll
        for (int j = 0; j < 16; ++j) tz += zpart[j];
        z_out[c * 128 + b] = tz;
    }
}

// ---------------- v = squash(s/z, axis=batch); optionally final output ------------------
__global__ __launch_bounds__(128) void squash_v(
    const float* __restrict__ s, const float* __restrict__ z,
    float* __restrict__ v_out, float* __restrict__ final_out)
{
    const int c = blockIdx.x, b = threadIdx.x;   // 10 blocks, 128 threads
    float sv[16];
    const float* sp = s + ((size_t)c * 128 + b) * 16;
    float zin = 1.f / z[c * 128 + b];
#pragma unroll
    for (int o = 0; o < 16; ++o) sv[o] = sp[o] * zin;
    __shared__ float m[16][129];
#pragma unroll
    for (int o = 0; o < 16; ++o) m[o][b] = sv[o] * sv[o];
    __syncthreads();
    __shared__ float sn[16];
    if (b < 16) {
        float t = 0.f;
        for (int i = 0; i < 128; ++i) t += m[b][i];
        sn[b] = t;
    }
    __syncthreads();
#pragma unroll
    for (int o = 0; o < 16; ++o) {
        float scale = sqrtf(sn[o]) / (1.f + sn[o]);
        float val = sv[o] * scale;
        if (final_out) final_out[((size_t)b * 10 + c) * 16 + o] = val;
        else           v_out[((size_t)c * 128 + b) * 16 + o] = val;
    }
}

// ---------------- launch ----------------------------------------------------------------
extern "C" void kernel_launch(void* const* d_in, const int* in_sizes, int n_in,
                              void* d_out, int out_size, void* d_ws, size_t ws_size,
                              hipStream_t stream)
{
    (void)in_sizes; (void)n_in; (void)out_size; (void)ws_size;
    const float* inp = (const float*)d_in[0];
    const float* cw  = (const float*)d_in[1];
    const float* cb  = (const float*)d_in[2];
    const float* rw  = (const float*)d_in[3];
    float* out = (float*)d_out;

    // workspace layout (bytes). pred aliases part+in_t+w_t (dead by then).
    char* ws = (char*)d_ws;
    float* part = (float*)(ws);                  // 28,311,552  [6,4608,256] f32
    f16*   in_t = (f16*)(ws + 28311552);         // 26,214,400  [128,20,20,256] f16
    f16*   w_t  = (f16*)(ws + 54525952);         // 10,616,832  [256,20736] f16
    float* pred = (float*)(ws);                  // 94,371,840  [10,128,1152,16] f32 (alias)
    float* x    = (float*)(ws + 94371840);       //  4,718,592  [128,1152,8]
    float* a    = (float*)(ws + 99090432);       //  5,898,240  [10,128,1152]
    float* s    = (float*)(ws + 104988672);      //     81,920  [10,128,16]
    float* z    = (float*)(ws + 105070592);      //      5,120  [10,128]
    float* v    = (float*)(ws + 105075712);      //     81,920  [10,128,16]
    // total ~105.2 MB

    transpose_input<<<dim3(128, 8, 13), dim3(32, 8), 0, stream>>>(inp, in_t);
    permute_w<<<256, 256, 0, stream>>>(cw, w_t);
    conv_mfma<<<dim3(72, 4, SPLITK), 256, 0, stream>>>(in_t, w_t, part);
    combine_squash<<<576, 256, 0, stream>>>(part, cb, x);
    pred_kernel<<<dim3(10, 36, 4), 256, 0, stream>>>(x, rw, pred);

    route2<<<dim3(10, 128), 256, 0, stream>>>(pred, nullptr, nullptr, nullptr, s, z);
    squash_v<<<10, 128, 0, stream>>>(s, z, v, nullptr);
    route2<<<dim3(10, 128), 256, 0, stream>>>(pred, v, nullptr, a, s, z);
    squash_v<<<10, 128, 0, stream>>>(s, z, v, nullptr);
    route2<<<dim3(10, 128), 256, 0, stream>>>(pred, v, a, nullptr, s, z);
    squash_v<<<10, 128, 0, stream>>>(s, z, nullptr, out);
}

// Round 5
// 287.423 us; speedup vs baseline: 4.8717x; 1.0440x over previous
//
#include <hip/hip_runtime.h>
#include <math.h>

typedef _Float16 f16;
typedef _Float16 f16x8 __attribute__((ext_vector_type(8)));
typedef float f32x4 __attribute__((ext_vector_type(4)));
typedef float f32x8 __attribute__((ext_vector_type(8)));

#define AS1 __attribute__((address_space(1)))
#define AS3 __attribute__((address_space(3)))

__device__ __forceinline__ void gld_lds16(const f16* g, f16* l) {
#if defined(__has_builtin) && __has_builtin(__builtin_amdgcn_global_load_lds)
    __builtin_amdgcn_global_load_lds((const AS1 void*)g, (AS3 void*)l, 16, 0, 0);
#else
    *(uint4*)l = *(const uint4*)g;
#endif
}

// ---------------- pre-pass 1: input [128,256,20,20] f32 -> [128,20,20,256] f16 ----------
__global__ __launch_bounds__(256) void transpose_input(
    const float* __restrict__ inp, f16* __restrict__ out)
{
    const int b = blockIdx.x, c0 = blockIdx.y * 32, p0 = blockIdx.z * 32;
    const int tx = threadIdx.x, ty = threadIdx.y;   // 32 x 8
    __shared__ float t[32][33];
#pragma unroll
    for (int j = 0; j < 4; ++j) {
        int c = ty + j * 8, p = p0 + tx;
        if (p < 400) t[c][tx] = inp[((size_t)b * 256 + c0 + c) * 400 + p];
    }
    __syncthreads();
#pragma unroll
    for (int j = 0; j < 4; ++j) {
        int p = p0 + ty + j * 8;
        if (p < 400) out[((size_t)b * 400 + p) * 256 + c0 + tx] = (f16)t[tx][ty + j * 8];
    }
}

// ---------------- pre-pass 2: conv_w [n=256][cin=256][p=81] f32 -> w_t[n][p*256+cin] f16 -
__global__ __launch_bounds__(256) void permute_w(
    const float* __restrict__ cw, f16* __restrict__ w_t)
{
    const int n = blockIdx.x, t = threadIdx.x;
    __shared__ f16 buf[81 * 258];
    const float* src = cw + (size_t)n * 20736;
    for (int i = t; i < 20736; i += 256) {
        int cin = i / 81, p = i - cin * 81;
        buf[p * 258 + cin] = (f16)src[i];
    }
    __syncthreads();
    f16* dst = w_t + (size_t)n * 20736;
    for (int j = t; j < 20736; j += 256) {
        int p = j >> 8, cin = j & 255;
        dst[j] = buf[p * 258 + cin];
    }
}

// ---------------- conv as implicit-im2col MFMA GEMM -------------------------------------
// M=4608, N=256, K chunks of 32 f16 (648 total, ordered kh,kw,cin). Block tile 128x128,
// BK=32, wave-tile 64x64 (4x4 frags of 16x16x32), double-buffered LDS, split-K=9.
// LDS layout (per tile, 128 rows x 32 f16): row-pair p (0..63) holds 8 chunks of 16B;
// phys slot ph8 = ((row&1)*4 + q4) ^ (p&7)  -> full 32-bank coverage per 16-lane batch.
// Staging identity: thread tid writes pair (tid>>3), slot (tid&7) -> dest f16 = tid*8;
// issue i covers pairs i*32..i*32+31 -> dest base i*2048 (NOT i*4096 -- R4 bug).
#define SPLITK 9
#define CITER 72   // 648 / 9
__global__ __launch_bounds__(256) void conv_mfma(
    const f16* __restrict__ in_t,   // [128,20,20,256]
    const f16* __restrict__ w_t,    // [256,20736]
    float* __restrict__ part)       // [9,4608,256]
{
    __shared__ f16 As[2][128 * 32];
    __shared__ f16 Bs[2][128 * 32];
    const int tid = threadIdx.x;
    const int lane = tid & 63, wave = tid >> 6;
    const int wm = wave >> 1, wn = wave & 1;
    const int m0 = blockIdx.x * 128, n0 = blockIdx.y * 128;
    const int kz = blockIdx.z;

    // staging source offsets: issue i covers phys pair = i*32 + (tid>>3), slot = tid&7
    int srcA[2], srcB[2];
#pragma unroll
    for (int i = 0; i < 2; ++i) {
        int pairp = i * 32 + (tid >> 3);
        int chunk8 = (tid & 7) ^ (pairp & 7);
        int e = chunk8 >> 2, q4 = chunk8 & 3;
        int m = m0 + pairp * 2 + e;
        int b = m / 36, hw = m - b * 36;
        int ho = hw / 6, wo = hw - ho * 6;
        srcA[i] = ((b * 20 + 2 * ho) * 20 + 2 * wo) * 256 + q4 * 8;
        int n = n0 + pairp * 2 + e;
        srcB[i] = n * 20736 + q4 * 8;
    }

    f32x4 acc[4][4] = {};
    const int row = lane & 15, quad = lane >> 4;
    const int kc_base = kz * CITER;

    // prologue: stage chunk 0 into buf 0
    {
        int kc = kc_base;
        int p = kc >> 3, cq = kc & 7;
        int kh = p / 9, kw = p - kh * 9;
        int koffA = (kh * 20 + kw) * 256 + cq * 32;
        int koffB = kc * 32;
#pragma unroll
        for (int i = 0; i < 2; ++i) {
            gld_lds16(in_t + srcA[i] + koffA, &As[0][i * 2048 + tid * 8]);
            gld_lds16(w_t + srcB[i] + koffB, &Bs[0][i * 2048 + tid * 8]);
        }
    }

    for (int it = 0; it < CITER; ++it) {
        const int cur = it & 1;
        __syncthreads();
        if (it + 1 < CITER) {
            int kc = kc_base + it + 1;
            int p = kc >> 3, cq = kc & 7;
            int kh = p / 9, kw = p - kh * 9;
            int koffA = (kh * 20 + kw) * 256 + cq * 32;
            int koffB = kc * 32;
#pragma unroll
            for (int i = 0; i < 2; ++i) {
                gld_lds16(in_t + srcA[i] + koffA, &As[cur ^ 1][i * 2048 + tid * 8]);
                gld_lds16(w_t + srcB[i] + koffB, &Bs[cur ^ 1][i * 2048 + tid * 8]);
            }
        }
        f16x8 af[4], bf[4];
#pragma unroll
        for (int mt = 0; mt < 4; ++mt) {
            int m = wm * 64 + mt * 16 + row;
            int ph8 = (((m & 1) << 2) + quad) ^ ((m >> 1) & 7);
            af[mt] = *(const f16x8*)(&As[cur][(m >> 1) * 64 + ph8 * 8]);
        }
#pragma unroll
        for (int nt = 0; nt < 4; ++nt) {
            int n = wn * 64 + nt * 16 + row;
            int ph8 = (((n & 1) << 2) + quad) ^ ((n >> 1) & 7);
            bf[nt] = *(const f16x8*)(&Bs[cur][(n >> 1) * 64 + ph8 * 8]);
        }
#pragma unroll
        for (int mt = 0; mt < 4; ++mt)
#pragma unroll
            for (int nt = 0; nt < 4; ++nt)
                acc[mt][nt] = __builtin_amdgcn_mfma_f32_16x16x32_f16(
                    af[mt], bf[nt], acc[mt][nt], 0, 0, 0);
    }

    // epilogue: coalesced stores to partial buffer
    const int col = lane & 15, qr = (lane >> 4) * 4;
    float* pb = part + (size_t)kz * 4608 * 256;
#pragma unroll
    for (int mt = 0; mt < 4; ++mt)
#pragma unroll
        for (int rg = 0; rg < 4; ++rg) {
            int m = m0 + wm * 64 + mt * 16 + qr + rg;
#pragma unroll
            for (int nt = 0; nt < 4; ++nt) {
                int n = n0 + wn * 64 + nt * 16 + col;
                pb[(size_t)m * 256 + n] = acc[mt][nt][rg];
            }
        }
}

// ---------------- split-K reduce + bias + capsule squash -> x[128,1152,8] ---------------
__global__ __launch_bounds__(256) void combine_squash(
    const float* __restrict__ part, const float* __restrict__ bias,
    float* __restrict__ x)
{
    int idx = blockIdx.x * 256 + threadIdx.x;   // over 4608*32
    int m = idx >> 5, o = idx & 31;
    int b = m / 36, hw = m - b * 36;
    float val[8];
#pragma unroll
    for (int k = 0; k < 8; ++k) val[k] = bias[k * 32 + o];
#pragma unroll
    for (int s = 0; s < SPLITK; ++s) {
        const float* p = part + ((size_t)s * 4608 + m) * 256 + o;
#pragma unroll
        for (int k = 0; k < 8; ++k) val[k] += p[k * 32];
    }
    float sn = 0.f;
#pragma unroll
    for (int k = 0; k < 8; ++k) sn += val[k] * val[k];
    float scale = sqrtf(sn) / (1.f + sn);
    int r = o * 36 + hw;
    float* xp = x + ((size_t)b * 1152 + r) * 8;
#pragma unroll
    for (int k = 0; k < 8; ++k) xp[k] = val[k] * scale;
}

// ---------------- pred[c,b,r,o] = sum_k x[b,r,k] * rw[c,r,k,o]  (stored f16) ------------
__global__ __launch_bounds__(256) void pred_kernel(
    const float* __restrict__ x, const float* __restrict__ rw,
    f16* __restrict__ pred)
{
    const int c = blockIdx.x, r0 = blockIdx.y * 32, b0 = blockIdx.z * 32;
    const int tid = threadIdx.x;
    const int o = tid & 15, rp = tid >> 4;
    const int r = r0 + rp * 2;

    float W0[8], W1[8];
    const float* wb = rw + ((size_t)(c * 1152 + r) * 8) * 16 + o;
#pragma unroll
    for (int k = 0; k < 8; ++k) { W0[k] = wb[k * 16]; W1[k] = wb[128 + k * 16]; }

    for (int b = b0; b < b0 + 32; ++b) {
        const float4* xp = (const float4*)(x + ((size_t)b * 1152 + r) * 8);
        float4 xa = xp[0], xb = xp[1], xc = xp[2], xd = xp[3];
        float p0 = xa.x * W0[0] + xa.y * W0[1] + xa.z * W0[2] + xa.w * W0[3]
                 + xb.x * W0[4] + xb.y * W0[5] + xb.z * W0[6] + xb.w * W0[7];
        float p1 = xc.x * W1[0] + xc.y * W1[1] + xc.z * W1[2] + xc.w * W1[3]
                 + xd.x * W1[4] + xd.y * W1[5] + xd.z * W1[6] + xd.w * W1[7];
        f16* pb = pred + ((size_t)(c * 128 + b) * 1152 + r) * 16 + o;
        pb[0]  = (f16)p0;
        pb[16] = (f16)p1;
    }
}

// ---------------- routing iteration with inline batch-squash ----------------------------
// s_in==null: e=1 (iter 0). Else: v_prev computed inline from s_in/z_in (squash over
// batch axis), a_new = (a_in?a_in:0)+pred.v_prev, e=exp(a_new), optional a_out.
// Writes s_out[c,b,16] (unnormalized sum e*pred) and z_out[c,b] (sum e).
__global__ __launch_bounds__(256) void route_f16(
    const f16* __restrict__ pred, const float* __restrict__ s_in,
    const float* __restrict__ z_in, const float* __restrict__ a_in,
    float* __restrict__ a_out, float* __restrict__ s_out, float* __restrict__ z_out)
{
    const int c = blockIdx.x, b = blockIdx.y, tid = threadIdx.x;
    const size_t base = (size_t)(c * 128 + b) * 1152;

    __shared__ float vs[16];
    __shared__ float mat[128][17];
    __shared__ float red[256][16];
    __shared__ float red2[16][16];
    __shared__ float zred[256];
    __shared__ float zpart[16];

    if (s_in) {   // inline squash(s_prev/z_prev, axis=batch) -> v_prev for this (c,b)
        if (tid < 128) {
            float zin = z_in ? 1.f / z_in[c * 128 + tid] : (1.f / 1152.f);
            const float* sp = s_in + (size_t)(c * 128 + tid) * 16;
#pragma unroll
            for (int o = 0; o < 16; ++o) mat[tid][o] = sp[o] * zin;
        }
        __syncthreads();
        if (tid < 16) {
            float sn = 0.f;
            for (int i = 0; i < 128; ++i) { float q = mat[i][tid]; sn += q * q; }
            vs[tid] = mat[b][tid] * sqrtf(sn) / (1.f + sn);
        }
        __syncthreads();
    }

    float sacc[16];
#pragma unroll
    for (int o = 0; o < 16; ++o) sacc[o] = 0.f;
    float zacc = 0.f;

    for (int r = tid; r < 1152; r += 256) {
        const f16x8* pp = (const f16x8*)(pred + (base + r) * 16);
        f32x8 q0 = __builtin_convertvector(pp[0], f32x8);
        f32x8 q1 = __builtin_convertvector(pp[1], f32x8);
        float e;
        if (s_in) {
            float contrib = 0.f;
#pragma unroll
            for (int j = 0; j < 8; ++j) contrib += q0[j] * vs[j] + q1[j] * vs[j + 8];
            float an = contrib + (a_in ? a_in[base + r] : 0.f);
            if (a_out) a_out[base + r] = an;
            e = __expf(an);
        } else {
            e = 1.f;
        }
#pragma unroll
        for (int j = 0; j < 8; ++j) { sacc[j] += e * q0[j]; sacc[j + 8] += e * q1[j]; }
        zacc += e;
    }

#pragma unroll
    for (int o = 0; o < 16; ++o) red[tid][o] = sacc[o];
    zred[tid] = zacc;
    __syncthreads();
    {
        const int o = tid & 15, seg = tid >> 4;
        float t = 0.f;
#pragma unroll
        for (int j = 0; j < 16; ++j) t += red[seg * 16 + j][o];
        red2[seg][o] = t;
        if (tid < 16) {
            float tz = 0.f;
#pragma unroll
            for (int j = 0; j < 16; ++j) tz += zred[tid * 16 + j];
            zpart[tid] = tz;
        }
    }
    __syncthreads();
    if (tid < 16) {
        float t = 0.f;
#pragma unroll
        for (int seg = 0; seg < 16; ++seg) t += red2[seg][tid];
        s_out[(size_t)(c * 128 + b) * 16 + tid] = t;
    } else if (tid == 16) {
        float tz = 0.f;
#pragma unroll
        for (int j = 0; j < 16; ++j) tz += zpart[j];
        z_out[c * 128 + b] = tz;
    }
}

// ---------------- final: v = squash(s/z, axis=batch) -> out[b,c,o] ----------------------
__global__ __launch_bounds__(128) void squash_final(
    const float* __restrict__ s, const float* __restrict__ z,
    float* __restrict__ out)
{
    const int c = blockIdx.x, b = threadIdx.x;   // 10 blocks, 128 threads
    float sv[16];
    const float* sp = s + ((size_t)c * 128 + b) * 16;
    float zin = 1.f / z[c * 128 + b];
#pragma unroll
    for (int o = 0; o < 16; ++o) sv[o] = sp[o] * zin;
    __shared__ float m[16][129];
#pragma unroll
    for (int o = 0; o < 16; ++o) m[o][b] = sv[o] * sv[o];
    __syncthreads();
    __shared__ float sn[16];
    if (b < 16) {
        float t = 0.f;
        for (int i = 0; i < 128; ++i) t += m[b][i];
        sn[b] = t;
    }
    __syncthreads();
#pragma unroll
    for (int o = 0; o < 16; ++o) {
        float scale = sqrtf(sn[o]) / (1.f + sn[o]);
        out[((size_t)b * 10 + c) * 16 + o] = sv[o] * scale;
    }
}

// ---------------- launch ----------------------------------------------------------------
extern "C" void kernel_launch(void* const* d_in, const int* in_sizes, int n_in,
                              void* d_out, int out_size, void* d_ws, size_t ws_size,
                              hipStream_t stream)
{
    (void)in_sizes; (void)n_in; (void)out_size; (void)ws_size;
    const float* inp = (const float*)d_in[0];
    const float* cw  = (const float*)d_in[1];
    const float* cb  = (const float*)d_in[2];
    const float* rw  = (const float*)d_in[3];
    float* out = (float*)d_out;

    char* ws = (char*)d_ws;
    float* part = (float*)(ws);                  // 42,467,328  [9,4608,256] f32
    f16*   in_t = (f16*)(ws + 42467328);         // 26,214,400  [128,20,20,256] f16
    f16*   w_t  = (f16*)(ws + 68681728);         // 10,616,832  [256,20736] f16
    float* x    = (float*)(ws + 79298560);       //  4,718,592  [128,1152,8] f32
    float* a    = (float*)(ws + 84017152);       //  5,898,240  [10,128,1152] f32
    float* sA   = (float*)(ws + 89915392);       //     81,920
    float* zA   = (float*)(ws + 89997312);       //      5,120
    float* sB   = (float*)(ws + 90002432);       //     81,920
    float* zB   = (float*)(ws + 90084352);       //      5,120
    f16*   pred = (f16*)(ws);                    // 47,185,920  [10,128,1152,16] f16
                                                 // (aliases part+in_t — dead by pred time)

    transpose_input<<<dim3(128, 8, 13), dim3(32, 8), 0, stream>>>(inp, in_t);
    permute_w<<<256, 256, 0, stream>>>(cw, w_t);
    conv_mfma<<<dim3(36, 2, SPLITK), 256, 0, stream>>>(in_t, w_t, part);
    combine_squash<<<576, 256, 0, stream>>>(part, cb, x);
    pred_kernel<<<dim3(10, 36, 4), 256, 0, stream>>>(x, rw, pred);

    route_f16<<<dim3(10, 128), 256, 0, stream>>>(pred, nullptr, nullptr, nullptr,
                                                 nullptr, sA, zA);           // iter 0
    route_f16<<<dim3(10, 128), 256, 0, stream>>>(pred, sA, zA, nullptr,
                                                 a, sB, zB);                 // iter 1
    route_f16<<<dim3(10, 128), 256, 0, stream>>>(pred, sB, zB, a,
                                                 nullptr, sA, zA);           // iter 2
    squash_final<<<10, 128, 0, stream>>>(sA, zA, out);
}

// Round 6
// 280.481 us; speedup vs baseline: 4.9923x; 1.0247x over previous
//
#include <hip/hip_runtime.h>
#include <math.h>

typedef _Float16 f16;
typedef _Float16 f16x8 __attribute__((ext_vector_type(8)));
typedef float f32x4 __attribute__((ext_vector_type(4)));
typedef float f32x8 __attribute__((ext_vector_type(8)));

#define AS1 __attribute__((address_space(1)))
#define AS3 __attribute__((address_space(3)))

__device__ __forceinline__ void gld_lds16(const f16* g, f16* l) {
#if defined(__has_builtin) && __has_builtin(__builtin_amdgcn_global_load_lds)
    __builtin_amdgcn_global_load_lds((const AS1 void*)g, (AS3 void*)l, 16, 0, 0);
#else
    *(uint4*)l = *(const uint4*)g;
#endif
}

// ---------------- pre-pass 1: input [128,256,20,20] f32 -> [128,20,20,256] f16 ----------
__global__ __launch_bounds__(256) void transpose_input(
    const float* __restrict__ inp, f16* __restrict__ out)
{
    const int b = blockIdx.x, c0 = blockIdx.y * 32, p0 = blockIdx.z * 32;
    const int tx = threadIdx.x, ty = threadIdx.y;   // 32 x 8
    __shared__ float t[32][33];
#pragma unroll
    for (int j = 0; j < 4; ++j) {
        int c = ty + j * 8, p = p0 + tx;
        if (p < 400) t[c][tx] = inp[((size_t)b * 256 + c0 + c) * 400 + p];
    }
    __syncthreads();
#pragma unroll
    for (int j = 0; j < 4; ++j) {
        int p = p0 + ty + j * 8;
        if (p < 400) out[((size_t)b * 400 + p) * 256 + c0 + tx] = (f16)t[tx][ty + j * 8];
    }
}

// ---------------- pre-pass 2: conv_w [n=256][cin=256][p=81] f32 -> w_t[n][p*256+cin] f16 -
__global__ __launch_bounds__(256) void permute_w(
    const float* __restrict__ cw, f16* __restrict__ w_t)
{
    const int n = blockIdx.x, t = threadIdx.x;
    __shared__ f16 buf[81 * 258];
    const float* src = cw + (size_t)n * 20736;
    for (int i = t; i < 20736; i += 256) {
        int cin = i / 81, p = i - cin * 81;
        buf[p * 258 + cin] = (f16)src[i];
    }
    __syncthreads();
    f16* dst = w_t + (size_t)n * 20736;
    for (int j = t; j < 20736; j += 256) {
        int p = j >> 8, cin = j & 255;
        dst[j] = buf[p * 258 + cin];
    }
}

// ---------------- conv as implicit-im2col MFMA GEMM -------------------------------------
// M=4608, N=256, K chunks of 32 f16 (648 total, ordered kh,kw,cin). Block tile 128x128,
// BK=32, wave-tile 64x64 (4x4 frags of 16x16x32), double-buffered LDS, split-K=18
// (grid 36x2x18 = 1296 blocks = 5.06/CU, matching the 32 KB-LDS occupancy cap).
// Partials stored f16 (18-split f16 == 9-split f32 bytes).
#define SPLITK 18
#define CITER 36   // 648 / 18
__global__ __launch_bounds__(256) void conv_mfma(
    const f16* __restrict__ in_t,   // [128,20,20,256]
    const f16* __restrict__ w_t,    // [256,20736]
    f16* __restrict__ part)         // [18,4608,256] f16
{
    __shared__ f16 As[2][128 * 32];
    __shared__ f16 Bs[2][128 * 32];
    const int tid = threadIdx.x;
    const int lane = tid & 63, wave = tid >> 6;
    const int wm = wave >> 1, wn = wave & 1;
    const int m0 = blockIdx.x * 128, n0 = blockIdx.y * 128;
    const int kz = blockIdx.z;

    // staging source offsets: issue i covers phys pair = i*32 + (tid>>3), slot = tid&7
    int srcA[2], srcB[2];
#pragma unroll
    for (int i = 0; i < 2; ++i) {
        int pairp = i * 32 + (tid >> 3);
        int chunk8 = (tid & 7) ^ (pairp & 7);
        int e = chunk8 >> 2, q4 = chunk8 & 3;
        int m = m0 + pairp * 2 + e;
        int b = m / 36, hw = m - b * 36;
        int ho = hw / 6, wo = hw - ho * 6;
        srcA[i] = ((b * 20 + 2 * ho) * 20 + 2 * wo) * 256 + q4 * 8;
        int n = n0 + pairp * 2 + e;
        srcB[i] = n * 20736 + q4 * 8;
    }

    f32x4 acc[4][4] = {};
    const int row = lane & 15, quad = lane >> 4;
    const int kc_base = kz * CITER;

    // prologue: stage chunk 0 into buf 0 (dest f16 offset = issue*2048 + tid*8)
    {
        int kc = kc_base;
        int p = kc >> 3, cq = kc & 7;
        int kh = p / 9, kw = p - kh * 9;
        int koffA = (kh * 20 + kw) * 256 + cq * 32;
        int koffB = kc * 32;
#pragma unroll
        for (int i = 0; i < 2; ++i) {
            gld_lds16(in_t + srcA[i] + koffA, &As[0][i * 2048 + tid * 8]);
            gld_lds16(w_t + srcB[i] + koffB, &Bs[0][i * 2048 + tid * 8]);
        }
    }

    for (int it = 0; it < CITER; ++it) {
        const int cur = it & 1;
        __syncthreads();
        if (it + 1 < CITER) {
            int kc = kc_base + it + 1;
            int p = kc >> 3, cq = kc & 7;
            int kh = p / 9, kw = p - kh * 9;
            int koffA = (kh * 20 + kw) * 256 + cq * 32;
            int koffB = kc * 32;
#pragma unroll
            for (int i = 0; i < 2; ++i) {
                gld_lds16(in_t + srcA[i] + koffA, &As[cur ^ 1][i * 2048 + tid * 8]);
                gld_lds16(w_t + srcB[i] + koffB, &Bs[cur ^ 1][i * 2048 + tid * 8]);
            }
        }
        f16x8 af[4], bf[4];
#pragma unroll
        for (int mt = 0; mt < 4; ++mt) {
            int m = wm * 64 + mt * 16 + row;
            int ph8 = (((m & 1) << 2) + quad) ^ ((m >> 1) & 7);
            af[mt] = *(const f16x8*)(&As[cur][(m >> 1) * 64 + ph8 * 8]);
        }
#pragma unroll
        for (int nt = 0; nt < 4; ++nt) {
            int n = wn * 64 + nt * 16 + row;
            int ph8 = (((n & 1) << 2) + quad) ^ ((n >> 1) & 7);
            bf[nt] = *(const f16x8*)(&Bs[cur][(n >> 1) * 64 + ph8 * 8]);
        }
#pragma unroll
        for (int mt = 0; mt < 4; ++mt)
#pragma unroll
            for (int nt = 0; nt < 4; ++nt)
                acc[mt][nt] = __builtin_amdgcn_mfma_f32_16x16x32_f16(
                    af[mt], bf[nt], acc[mt][nt], 0, 0, 0);
    }

    // epilogue: f16 stores to partial buffer
    const int col = lane & 15, qr = (lane >> 4) * 4;
    f16* pb = part + (size_t)kz * 4608 * 256;
#pragma unroll
    for (int mt = 0; mt < 4; ++mt)
#pragma unroll
        for (int rg = 0; rg < 4; ++rg) {
            int m = m0 + wm * 64 + mt * 16 + qr + rg;
#pragma unroll
            for (int nt = 0; nt < 4; ++nt) {
                int n = n0 + wn * 64 + nt * 16 + col;
                pb[(size_t)m * 256 + n] = (f16)acc[mt][nt][rg];
            }
        }
}

// ---------------- split-K reduce + bias + capsule squash -> x[128,1152,8] ---------------
__global__ __launch_bounds__(256) void combine_squash(
    const f16* __restrict__ part, const float* __restrict__ bias,
    float* __restrict__ x)
{
    int idx = blockIdx.x * 256 + threadIdx.x;   // over 4608*32
    int m = idx >> 5, o = idx & 31;
    int b = m / 36, hw = m - b * 36;
    float val[8];
#pragma unroll
    for (int k = 0; k < 8; ++k) val[k] = bias[k * 32 + o];
#pragma unroll
    for (int s = 0; s < SPLITK; ++s) {
        const f16* p = part + ((size_t)s * 4608 + m) * 256 + o;
#pragma unroll
        for (int k = 0; k < 8; ++k) val[k] += (float)p[k * 32];
    }
    float sn = 0.f;
#pragma unroll
    for (int k = 0; k < 8; ++k) sn += val[k] * val[k];
    float scale = sqrtf(sn) / (1.f + sn);
    int r = o * 36 + hw;
    float* xp = x + ((size_t)b * 1152 + r) * 8;
#pragma unroll
    for (int k = 0; k < 8; ++k) xp[k] = val[k] * scale;
}

// ---------------- pred (f16) + fused routing-iter-0 s-accumulation ----------------------
// pred[c,b,r,o] = sum_k x[b,r,k]*rw[c,r,k,o]; also s0[c,b,o] += sum_r pred (e=1 iter,
// z0 = 1152 handled downstream via the z_in==null path). s0 must be pre-zeroed.
__global__ __launch_bounds__(256) void pred_s0(
    const float* __restrict__ x, const float* __restrict__ rw,
    f16* __restrict__ pred, float* __restrict__ s0)
{
    const int c = blockIdx.x, r0 = blockIdx.y * 32, b0 = blockIdx.z * 32;
    const int tid = threadIdx.x;
    const int o = tid & 15, rp = tid >> 4;
    const int r = r0 + rp * 2;

    __shared__ float s_sh[32 * 16];
    s_sh[tid] = 0.f; s_sh[tid + 256] = 0.f;

    float W0[8], W1[8];
    const float* wb = rw + ((size_t)(c * 1152 + r) * 8) * 16 + o;
#pragma unroll
    for (int k = 0; k < 8; ++k) { W0[k] = wb[k * 16]; W1[k] = wb[128 + k * 16]; }
    __syncthreads();

    for (int bb = 0; bb < 32; ++bb) {
        const int b = b0 + bb;
        const float4* xp = (const float4*)(x + ((size_t)b * 1152 + r) * 8);
        float4 xa = xp[0], xb = xp[1], xc = xp[2], xd = xp[3];
        float p0 = xa.x * W0[0] + xa.y * W0[1] + xa.z * W0[2] + xa.w * W0[3]
                 + xb.x * W0[4] + xb.y * W0[5] + xb.z * W0[6] + xb.w * W0[7];
        float p1 = xc.x * W1[0] + xc.y * W1[1] + xc.z * W1[2] + xc.w * W1[3]
                 + xd.x * W1[4] + xd.y * W1[5] + xd.z * W1[6] + xd.w * W1[7];
        f16* pb = pred + ((size_t)(c * 128 + b) * 1152 + r) * 16 + o;
        pb[0]  = (f16)p0;
        pb[16] = (f16)p1;
        // iter-0 accumulation: sum over this block's 32 routes
        float ps = p0 + p1;
        ps += __shfl_xor(ps, 16);
        ps += __shfl_xor(ps, 32);           // lanes 0-15: sum over wave's 4 r-pairs
        if ((tid & 63) < 16) atomicAdd(&s_sh[bb * 16 + o], ps);
    }
    __syncthreads();
    for (int i = tid; i < 512; i += 256) {
        int bb = i >> 4, oo = i & 15;
        atomicAdd(&s0[((size_t)c * 128 + b0 + bb) * 16 + oo], s_sh[i]);
    }
}

// ---------------- routing iteration with inline batch-squash ----------------------------
// v_prev computed inline from s_in/z_in (squash over batch axis; z_in==null -> 1/1152),
// a_new = (a_in?a_in:0)+pred.v_prev, e=exp(a_new), optional a_out.
// Writes s_out[c,b,16] (unnormalized sum e*pred) and z_out[c,b] (sum e).
__global__ __launch_bounds__(256) void route_f16(
    const f16* __restrict__ pred, const float* __restrict__ s_in,
    const float* __restrict__ z_in, const float* __restrict__ a_in,
    float* __restrict__ a_out, float* __restrict__ s_out, float* __restrict__ z_out)
{
    const int c = blockIdx.x, b = blockIdx.y, tid = threadIdx.x;
    const size_t base = (size_t)(c * 128 + b) * 1152;

    __shared__ float vs[16];
    __shared__ float mat[128][17];
    __shared__ float red[256][16];
    __shared__ float red2[16][16];
    __shared__ float zred[256];
    __shared__ float zpart[16];

    {   // inline squash(s_prev/z_prev, axis=batch) -> v_prev for this (c,b)
        if (tid < 128) {
            float zin = z_in ? 1.f / z_in[c * 128 + tid] : (1.f / 1152.f);
            const float* sp = s_in + (size_t)(c * 128 + tid) * 16;
#pragma unroll
            for (int o = 0; o < 16; ++o) mat[tid][o] = sp[o] * zin;
        }
        __syncthreads();
        if (tid < 16) {
            float sn = 0.f;
            for (int i = 0; i < 128; ++i) { float q = mat[i][tid]; sn += q * q; }
            vs[tid] = mat[b][tid] * sqrtf(sn) / (1.f + sn);
        }
        __syncthreads();
    }

    float sacc[16];
#pragma unroll
    for (int o = 0; o < 16; ++o) sacc[o] = 0.f;
    float zacc = 0.f;

    for (int r = tid; r < 1152; r += 256) {
        const f16x8* pp = (const f16x8*)(pred + (base + r) * 16);
        f32x8 q0 = __builtin_convertvector(pp[0], f32x8);
        f32x8 q1 = __builtin_convertvector(pp[1], f32x8);
        float contrib = 0.f;
#pragma unroll
        for (int j = 0; j < 8; ++j) contrib += q0[j] * vs[j] + q1[j] * vs[j + 8];
        float an = contrib + (a_in ? a_in[base + r] : 0.f);
        if (a_out) a_out[base + r] = an;
        float e = __expf(an);
#pragma unroll
        for (int j = 0; j < 8; ++j) { sacc[j] += e * q0[j]; sacc[j + 8] += e * q1[j]; }
        zacc += e;
    }

#pragma unroll
    for (int o = 0; o < 16; ++o) red[tid][o] = sacc[o];
    zred[tid] = zacc;
    __syncthreads();
    {
        const int o = tid & 15, seg = tid >> 4;
        float t = 0.f;
#pragma unroll
        for (int j = 0; j < 16; ++j) t += red[seg * 16 + j][o];
        red2[seg][o] = t;
        if (tid < 16) {
            float tz = 0.f;
#pragma unroll
            for (int j = 0; j < 16; ++j) tz += zred[tid * 16 + j];
            zpart[tid] = tz;
        }
    }
    __syncthreads();
    if (tid < 16) {
        float t = 0.f;
#pragma unroll
        for (int seg = 0; seg < 16; ++seg) t += red2[seg][tid];
        s_out[(size_t)(c * 128 + b) * 16 + tid] = t;
    } else if (tid == 16) {
        float tz = 0.f;
#pragma unroll
        for (int j = 0; j < 16; ++j) tz += zpart[j];
        z_out[c * 128 + b] = tz;
    }
}

// ---------------- final: v = squash(s/z, axis=batch) -> out[b,c,o] ----------------------
__global__ __launch_bounds__(128) void squash_final(
    const float* __restrict__ s, const float* __restrict__ z,
    float* __restrict__ out)
{
    const int c = blockIdx.x, b = threadIdx.x;   // 10 blocks, 128 threads
    float sv[16];
    const float* sp = s + ((size_t)c * 128 + b) * 16;
    float zin = 1.f / z[c * 128 + b];
#pragma unroll
    for (int o = 0; o < 16; ++o) sv[o] = sp[o] * zin;
    __shared__ float m[16][129];
#pragma unroll
    for (int o = 0; o < 16; ++o) m[o][b] = sv[o] * sv[o];
    __syncthreads();
    __shared__ float sn[16];
    if (b < 16) {
        float t = 0.f;
        for (int i = 0; i < 128; ++i) t += m[b][i];
        sn[b] = t;
    }
    __syncthreads();
#pragma unroll
    for (int o = 0; o < 16; ++o) {
        float scale = sqrtf(sn[o]) / (1.f + sn[o]);
        out[((size_t)b * 10 + c) * 16 + o] = sv[o] * scale;
    }
}

// ---------------- launch ----------------------------------------------------------------
extern "C" void kernel_launch(void* const* d_in, const int* in_sizes, int n_in,
                              void* d_out, int out_size, void* d_ws, size_t ws_size,
                              hipStream_t stream)
{
    (void)in_sizes; (void)n_in; (void)out_size; (void)ws_size;
    const float* inp = (const float*)d_in[0];
    const float* cw  = (const float*)d_in[1];
    const float* cb  = (const float*)d_in[2];
    const float* rw  = (const float*)d_in[3];
    float* out = (float*)d_out;

    // workspace layout (bytes), total ~94.8 MB:
    //   [0, 42.5M)   part f16 [18,4608,256]   (conv -> combine)
    //   [0, 47.2M)   pred f16 [10,128,1152,16] (aliases part; part dead after combine)
    //   [47.2M, ..)  x, a, sA, zA, sB, zB
    //   [58.0M, ..)  in_t (conv-time only), w_t (conv-time only)
    char* ws = (char*)d_ws;
    f16*   part = (f16*)(ws);                    // 42,467,328
    f16*   pred = (f16*)(ws);                    // 47,185,920 (alias)
    float* x    = (float*)(ws + 47185920);       //  4,718,592
    float* a    = (float*)(ws + 51904512);       //  5,898,240
    float* sA   = (float*)(ws + 57802752);       //     81,920
    float* zA   = (float*)(ws + 57884672);       //      5,120
    float* sB   = (float*)(ws + 57889792);       //     81,920
    float* zB   = (float*)(ws + 57971712);       //      5,120
    f16*   in_t = (f16*)(ws + 57976832);         // 26,214,400
    f16*   w_t  = (f16*)(ws + 84191232);         // 10,616,832 -> end 94,808,064

    transpose_input<<<dim3(128, 8, 13), dim3(32, 8), 0, stream>>>(inp, in_t);
    permute_w<<<256, 256, 0, stream>>>(cw, w_t);
    conv_mfma<<<dim3(36, 2, SPLITK), 256, 0, stream>>>(in_t, w_t, part);
    combine_squash<<<576, 256, 0, stream>>>(part, cb, x);

    hipMemsetAsync(sA, 0, 81920, stream);
    pred_s0<<<dim3(10, 36, 4), 256, 0, stream>>>(x, rw, pred, sA);   // pred + iter0 s

    route_f16<<<dim3(10, 128), 256, 0, stream>>>(pred, sA, nullptr, nullptr,
                                                 a, sB, zB);          // iter 1 (z0=1152)
    route_f16<<<dim3(10, 128), 256, 0, stream>>>(pred, sB, zB, a,
                                                 nullptr, sA, zA);    // iter 2
    squash_final<<<10, 128, 0, stream>>>(sA, zA, out);
}